// Round 14
// baseline (394.226 us; speedup 1.0000x reference)
//
#include <hip/hip_runtime.h>
#include <hip/hip_cooperative_groups.h>

namespace cg = cooperative_groups;

#define TPB 256

typedef short bf16x8 __attribute__((ext_vector_type(8)));
typedef float f32x4 __attribute__((ext_vector_type(4)));

__device__ inline unsigned short f2bf(float f) {
    unsigned int u = __float_as_uint(f);
    unsigned int r = (u + 0x7fffu + ((u >> 16) & 1u)) >> 16;
    return (unsigned short)r;
}
__device__ inline float bf2f(unsigned short h) {
    return __uint_as_float(((unsigned int)h) << 16);
}

__device__ __forceinline__ void gl16(void* lds, const void* g) {
    __builtin_amdgcn_global_load_lds(
        (const __attribute__((address_space(1))) unsigned int*)g,
        (__attribute__((address_space(3))) unsigned int*)lds, 16, 0, 0);
}

// ================= device phase bodies (shared by mega + fallback) =================

// ---- prep: xbf (+sq ch), w1r/w2r/w3r reorders, zerob (flat grid-stride) ----
__device__ __forceinline__ void dev_prep(int gi, int stride,
    const float* __restrict__ x, const float* __restrict__ w1,
    const float* __restrict__ w2, const float* __restrict__ w3,
    unsigned short* __restrict__ xbf, unsigned short* __restrict__ w1r,
    unsigned short* __restrict__ w2r, unsigned short* __restrict__ w3r,
    unsigned short* __restrict__ zerob)
{
    const int NX = 262144, E1 = NX + 13056, E2 = E1 + 479232, E3 = E2 + 368640, TOT = E3 + 64;
    for (int i = gi; i < TOT; i += stride) {
        if (i < NX) {
            int b = i >> 14, px = i & 16383;
            const float* xb = x + (size_t)b * 49152 + px;
            float v0 = xb[0], v1 = xb[16384], v2 = xb[32768];
            ushort4 v;
            v.x = f2bf(v0); v.y = f2bf(v1); v.z = f2bf(v2);
            v.w = f2bf(v0 * v0 + v1 * v1 + v2 * v2);
            *(ushort4*)&xbf[(size_t)i * 4] = v;
        } else if (i < E1) {
            int idx = i - NX;
            int o = idx / 136, d = idx - o * 136;
            int tp = d >> 2, c = d & 3;
            float v = 0.f;
            if (tp < 30) {
                int ki = tp / 6, kj = tp - 6 * ki;
                if (kj < 5) v = (c < 3) ? w1[o * 75 + c * 25 + ki * 5 + kj] : -0.5f;
            }
            w1r[idx] = f2bf(v);
        } else if (i < E2) {
            int idx = i - E1;
            int c = idx & 31; int r = idx >> 5;
            int o = r % 192; r /= 192;
            int tap = r % 26; int cgx = r / 26;
            float v = 0.f;
            if (tap < 25) v = w2[((size_t)o * 96 + cgx * 32 + c) * 25 + tap];
            w2r[idx] = f2bf(v);
        } else if (i < E3) {
            int idx = i - E2;
            int c = idx & 31; int r = idx >> 5;
            int o = r % 192; r /= 192;
            int tap = r % 10; int cgx = r / 10;
            float v = 0.f;
            if (tap < 9) v = w3[((size_t)o * 192 + cgx * 32 + c) * 9 + tap];
            w3r[idx] = f2bf(v);
        } else {
            zerob[i - E3] = 0;
        }
    }
}

// ---- wn row-norm for one o (one 64-lane wave) ----
__device__ __forceinline__ void dev_wn(int o, int lane,
    const float* __restrict__ w1, const float* __restrict__ w2,
    const float* __restrict__ w3,
    float* __restrict__ wn1, float* __restrict__ wn2, float* __restrict__ wn3)
{
    const float* row; float* dst; int D;
    if (o < 96)       { row = w1 + (size_t)o * 75;           D = 75;   dst = wn1 + o; }
    else if (o < 288) { int r = o - 96;  row = w2 + (size_t)r * 2400; D = 2400; dst = wn2 + r; }
    else              { int r = o - 288; row = w3 + (size_t)r * 1728; D = 1728; dst = wn3 + r; }
    float acc = 0.f;
    for (int i = lane; i < D; i += 64) { float v = row[i]; acc += v * v; }
    #pragma unroll
    for (int off = 32; off >= 1; off >>= 1) acc += __shfl_down(acc, off);
    if (lane == 0) *dst = acc;
}

// ---- conv1 tile (t in [0,1024)) ----
__device__ __forceinline__ void dev_conv1(int t, int tid, unsigned char* smem,
    const unsigned short* __restrict__ xbf, const unsigned short* __restrict__ w1r,
    const float* __restrict__ wn,
    const float* __restrict__ stdp, const float* __restrict__ biasp,
    const float* __restrict__ alphap,
    unsigned short* __restrict__ out, float* __restrict__ sqout)
{
    unsigned short* in_s = (unsigned short*)smem;           // 1760 elems
    unsigned short* w_s  = (unsigned short*)(smem + 3520);  // 13056 elems
    __syncthreads();

    int tx = t & 7; t >>= 3;
    int ty = t & 7; t >>= 3;
    int b = t;
    int x0 = tx * 16, y0 = ty * 16;
    int lane = tid & 63, wv = tid >> 6;
    int col = lane & 15, kg = lane >> 4;

    for (int idx = tid; idx < 21 * 20; idx += 256) {
        int py = idx / 20, px = idx - py * 20;
        int gy = y0 - 2 + py, gx = x0 - 2 + px;
        ushort4 v = make_ushort4(0, 0, 0, 0);
        if (gy >= 0 && gy < 128 && gx >= 0 && gx < 128)
            v = *(const ushort4*)&xbf[(((size_t)b * 128 + gy) * 128 + gx) * 4];
        *(ushort4*)&in_s[idx * 4] = v;
    }
    for (int idx = tid; idx < 1632; idx += 256)
        *(bf16x8*)&w_s[idx * 8] = *(const bf16x8*)&w1r[idx * 8];
    __syncthreads();

    f32x4 acc[6][4];
    #pragma unroll
    for (int mt = 0; mt < 6; ++mt)
        #pragma unroll
        for (int n = 0; n < 4; ++n) acc[mt][n] = (f32x4){0.f, 0.f, 0.f, 0.f};

    #pragma unroll
    for (int ks = 0; ks < 4; ++ks) {
        int tap0 = ks * 8 + kg * 2;
        int ki = tap0 / 6, kj = tap0 - 6 * ki;
        bf16x8 bfrag[4];
        #pragma unroll
        for (int n = 0; n < 4; ++n) {
            int row = wv * 4 + n + ki;
            int ix = col + kj;
            const unsigned short* p = &in_s[(row * 20 + ix) * 4];
            union { bf16x8 v; uint2 u[2]; } tmp;
            tmp.u[0] = *(const uint2*)p;
            tmp.u[1] = *(const uint2*)(p + 4);
            bfrag[n] = tmp.v;
        }
        bf16x8 afrag[6];
        #pragma unroll
        for (int mt = 0; mt < 6; ++mt)
            afrag[mt] = *(const bf16x8*)&w_s[(mt * 16 + col) * 136 + ks * 32 + kg * 8];
        #pragma unroll
        for (int mt = 0; mt < 6; ++mt)
            #pragma unroll
            for (int n = 0; n < 4; ++n)
                acc[mt][n] = __builtin_amdgcn_mfma_f32_16x16x32_bf16(
                    afrag[mt], bfrag[n], acc[mt][n], 0, 0, 0);
    }

    float stdv = stdp[0], biasv = biasp[0];
    float inv2s2 = 1.f / (2.f * stdv * stdv);
    float a00 = alphap[0], a01 = alphap[1], a10 = alphap[2], a11 = alphap[3];
    int dx = col & 1;
    float ax0 = dx ? a01 : a00;
    float ax1 = dx ? a11 : a10;

    float sqa[2] = {0.f, 0.f};
    #pragma unroll
    for (int mt = 0; mt < 6; ++mt) {
        #pragma unroll
        for (int p2 = 0; p2 < 2; ++p2) {
            unsigned short res[4];
            #pragma unroll
            for (int r = 0; r < 4; ++r) {
                int o = mt * 16 + kg * 4 + r;
                float wno = wn[o];
                float d20 = fmaxf(wno - 2.f * acc[mt][2 * p2][r], 0.f);
                float d21 = fmaxf(wno - 2.f * acc[mt][2 * p2 + 1][r], 0.f);
                float g0 = __expf(-d20 * inv2s2);
                float g1 = __expf(-d21 * inv2s2);
                g0 = (g0 >= biasv) ? g0 : 0.f;
                g1 = (g1 >= biasv) ? g1 : 0.f;
                float s = ax0 * g0 + ax1 * g1;
                s += __shfl_xor(s, 1);
                res[r] = f2bf(0.25f * s);
                float vv = bf2f(res[r]);
                sqa[p2] += vv * vv;
            }
            if (dx == 0) {
                int yo = ty * 8 + wv * 2 + p2, xo = tx * 8 + (col >> 1);
                *(ushort4*)&out[(((size_t)b * 64 + yo) * 64 + xo) * 96 + mt * 16 + kg * 4] =
                    make_ushort4(res[0], res[1], res[2], res[3]);
            }
        }
    }
    #pragma unroll
    for (int p2 = 0; p2 < 2; ++p2) {
        float s = sqa[p2];
        s += __shfl_xor(s, 16);
        s += __shfl_xor(s, 32);
        if (dx == 0 && kg == 0) {
            int yo = ty * 8 + wv * 2 + p2, xo = tx * 8 + (col >> 1);
            sqout[((size_t)b * 64 + yo) * 64 + xo] = s;
        }
    }
}

// ---- conv2 tile (t in [0,512)): 192o x 128px, zero-skip before weights ----
__device__ __forceinline__ void dev_conv2(int t, int tid, unsigned char* smem,
    const unsigned short* __restrict__ hin, const unsigned short* __restrict__ wt2,
    const float* __restrict__ sq1, const float* __restrict__ wn,
    const float* __restrict__ stdp, const float* __restrict__ biasp,
    const float* __restrict__ alphap, const unsigned short* __restrict__ zerob,
    unsigned short* __restrict__ hout)
{
    unsigned short* in_s = (unsigned short*)smem;             // 7680 elems
    unsigned short* w_s  = (unsigned short*)(smem + 15360);   // 24576 elems ([cur]=cur*12288)
    float* sq_s          = (float*)(smem + 64512);            // 240
    int* s_nz            = (int*)(smem + 65472);              // 4

    int xt = t & 3; t >>= 2;
    int yt = t & 7; t >>= 3;
    int b = t;
    int x0 = xt * 16, y0 = yt * 8;
    int lane = tid & 63, wid = tid >> 6;
    int wave_m = wid >> 1, wave_n = wid & 1;
    int col = lane & 15, kg = lane >> 4;
    int coly = col >> 3, colx = col & 7;

    if (tid < 240) {
        int r = tid / 20, c = tid - r * 20;
        int gy = y0 - 2 + r, gx = x0 - 2 + c;
        float v = 0.f;
        if (gy >= 0 && gy < 64 && gx >= 0 && gx < 64)
            v = sq1[((size_t)b * 64 + gy) * 64 + gx];
        sq_s[tid] = v;
    }

    f32x4 acc[6][4];
    #pragma unroll
    for (int mt = 0; mt < 6; ++mt)
        #pragma unroll
        for (int nt = 0; nt < 4; ++nt) acc[mt][nt] = (f32x4){0.f, 0.f, 0.f, 0.f};

    for (int cgx = 0; cgx < 3; ++cgx) {
        #pragma unroll
        for (int i = 0; i < 4; ++i) {
            int chunk = tid + i * 256;
            if (chunk < 960) {
                int px = chunk >> 2, c16 = chunk & 3;
                int iy = px / 20, ix = px - iy * 20;
                int gy = y0 - 2 + iy, gx = x0 - 2 + ix;
                const void* src = (gy >= 0 && gy < 64 && gx >= 0 && gx < 64)
                    ? (const void*)&hin[(((size_t)b * 64 + gy) * 64 + gx) * 96 + cgx * 32 + c16 * 8]
                    : (const void*)zerob;
                gl16(&in_s[chunk * 8], src);
            }
        }
        __syncthreads();

        unsigned int nzb = 0;
        #pragma unroll
        for (int i = 0; i < 4; ++i) {
            int chunk = tid + i * 256;
            if (chunk < 960) {
                uint4 v = *(const uint4*)&in_s[chunk * 8];
                nzb |= v.x | v.y | v.z | v.w;
            }
        }
        bool any = __any(nzb != 0);
        if (lane == 0) s_nz[wid] = any ? 1 : 0;
        __syncthreads();
        if (s_nz[0] | s_nz[1] | s_nz[2] | s_nz[3]) {
            #pragma unroll
            for (int i = 0; i < 6; ++i) {
                int chunk = tid + i * 256;
                int tp = chunk / 768, rem = chunk - tp * 768;
                gl16(&w_s[tp * 6144 + rem * 8],
                     &wt2[(((size_t)cgx * 26 + tp) * 192) * 32 + rem * 8]);
            }
            __syncthreads();
            for (int pr = 0; pr < 13; ++pr) {
                int cur = pr & 1;
                if (pr < 12) {
                    #pragma unroll
                    for (int i = 0; i < 6; ++i) {
                        int chunk = tid + i * 256;
                        int tp = chunk / 768, rem = chunk - tp * 768;
                        gl16(&w_s[(cur ^ 1) * 12288 + tp * 6144 + rem * 8],
                             &wt2[(((size_t)cgx * 26 + (pr + 1) * 2 + tp) * 192) * 32 + rem * 8]);
                    }
                }
                #pragma unroll
                for (int t2 = 0; t2 < 2; ++t2) {
                    int tap = pr * 2 + t2;
                    int ki = tap / 5, kj = tap - 5 * ki;
                    if (tap >= 25) { ki = 0; kj = 0; }
                    bf16x8 bfrag[4], afrag[6];
                    #pragma unroll
                    for (int nt = 0; nt < 4; ++nt) {
                        int yy = 2 * nt + coly + ki;
                        int xx = wave_n * 8 + colx + kj;
                        bfrag[nt] = *(const bf16x8*)&in_s[(yy * 20 + xx) * 32 + kg * 8];
                    }
                    #pragma unroll
                    for (int mt = 0; mt < 6; ++mt)
                        afrag[mt] = *(const bf16x8*)
                            &w_s[cur * 12288 + t2 * 6144 + (wave_m * 96 + mt * 16 + col) * 32 + kg * 8];
                    #pragma unroll
                    for (int mt = 0; mt < 6; ++mt)
                        #pragma unroll
                        for (int nt = 0; nt < 4; ++nt)
                            acc[mt][nt] = __builtin_amdgcn_mfma_f32_16x16x32_bf16(
                                afrag[mt], bfrag[nt], acc[mt][nt], 0, 0, 0);
                }
                __syncthreads();
            }
        }
    }

    float stdv = stdp[0], biasv = biasp[0];
    float inv2s2 = 1.f / (2.f * stdv * stdv);
    float a_own = alphap[coly * 2 + (col & 1)];
    #pragma unroll
    for (int nt = 0; nt < 4; ++nt) {
        int ly = 2 * nt + coly + 2;
        int lx = wave_n * 8 + colx + 2;
        float pnv = 0.f;
        #pragma unroll
        for (int dy = -2; dy <= 2; ++dy)
            #pragma unroll
            for (int dx2 = -2; dx2 <= 2; ++dx2)
                pnv += sq_s[(ly + dy) * 20 + (lx + dx2)];
        int x = x0 + wave_n * 8 + colx;
        int yo = (y0 >> 1) + nt;
        int xo = x >> 1;
        #pragma unroll
        for (int mt = 0; mt < 6; ++mt) {
            int ob = wave_m * 96 + mt * 16 + (kg << 2);
            unsigned short res[4];
            #pragma unroll
            for (int r = 0; r < 4; ++r) {
                float d2 = fmaxf(pnv + wn[ob + r] - 2.f * acc[mt][nt][r], 0.f);
                float g = __expf(-d2 * inv2s2);
                g = (g >= biasv) ? g : 0.f;
                g *= a_own;
                g += __shfl_xor(g, 1);
                g += __shfl_xor(g, 8);
                res[r] = f2bf(0.25f * g);
            }
            if (((col & 1) == 0) && ((col & 8) == 0)) {
                *(ushort4*)&hout[(((size_t)b * 32 + yo) * 32 + xo) * 192 + ob] =
                    make_ushort4(res[0], res[1], res[2], res[3]);
            }
        }
    }
}

// ---- conv3 tile (t in [0,512)): 4 waves x (48o x 64px), inline pn3 ----
__device__ __forceinline__ void dev_conv3(int t, int tid, unsigned char* smem,
    const unsigned short* __restrict__ hin, const unsigned short* __restrict__ wt3,
    const float* __restrict__ wn,
    const float* __restrict__ stdp, const float* __restrict__ biasp,
    const unsigned short* __restrict__ zerob, unsigned short* __restrict__ hout)
{
    unsigned short* in_s = (unsigned short*)smem;             // 5760 elems
    unsigned short* w_s  = (unsigned short*)(smem + 11520);   // 12288 elems ([cur]=cur*6144)
    float* pnacc         = (float*)(smem + 36096);            // 180

    int sp = t & 7; t >>= 3;
    int ot = t & 3; int b = t >> 2;
    int x0 = (sp & 1) * 16, y0 = (sp >> 1) * 8, o0 = ot * 96;
    int lane = tid & 63, wid = tid >> 6;
    int om = wid >> 1, wn2 = wid & 1;
    int col = lane & 15, kg = lane >> 4;
    int coly = col >> 3, colx = col & 7;

    if (tid < 180) pnacc[tid] = 0.f;

    f32x4 acc[3][4];
    #pragma unroll
    for (int mt = 0; mt < 3; ++mt)
        #pragma unroll
        for (int nt = 0; nt < 4; ++nt) acc[mt][nt] = (f32x4){0.f, 0.f, 0.f, 0.f};

    for (int cgx = 0; cgx < 6; ++cgx) {
        #pragma unroll
        for (int i = 0; i < 3; ++i) {
            int chunk = tid + i * 256;
            if (chunk < 720) {
                int px = chunk >> 2, c16 = chunk & 3;
                int iy = px / 18, ix = px - iy * 18;
                int gy = y0 - 1 + iy, gx = x0 - 1 + ix;
                const void* src = (gy >= 0 && gy < 32 && gx >= 0 && gx < 32)
                    ? (const void*)&hin[(((size_t)b * 32 + gy) * 32 + gx) * 192 + cgx * 32 + c16 * 8]
                    : (const void*)zerob;
                gl16(&in_s[chunk * 8], src);
            }
        }
        #pragma unroll
        for (int i = 0; i < 3; ++i) {
            int chunk = tid + i * 256;
            int tp = chunk / 384, rem = chunk - tp * 384;
            gl16(&w_s[tp * 3072 + rem * 8],
                 &wt3[(((size_t)cgx * 10 + tp) * 192 + o0) * 32 + rem * 8]);
        }
        __syncthreads();

        if (tid < 180) {
            const unsigned short* p = &in_s[tid * 32];
            float a = 0.f;
            #pragma unroll
            for (int c = 0; c < 32; c += 8) {
                bf16x8 v = *(const bf16x8*)&p[c];
                #pragma unroll
                for (int j = 0; j < 8; ++j) { float f = bf2f((unsigned short)v[j]); a += f * f; }
            }
            pnacc[tid] += a;
        }

        for (int pr = 0; pr < 5; ++pr) {
            int cur = pr & 1;
            if (pr < 4) {
                #pragma unroll
                for (int i = 0; i < 3; ++i) {
                    int chunk = tid + i * 256;
                    int tp = chunk / 384, rem = chunk - tp * 384;
                    gl16(&w_s[(cur ^ 1) * 6144 + tp * 3072 + rem * 8],
                         &wt3[(((size_t)cgx * 10 + (pr + 1) * 2 + tp) * 192 + o0) * 32 + rem * 8]);
                }
            }
            #pragma unroll
            for (int t2 = 0; t2 < 2; ++t2) {
                int tap = pr * 2 + t2;
                int ki = tap / 3, kj = tap - 3 * ki;
                if (tap >= 9) { ki = 0; kj = 0; }
                bf16x8 bfrag[4], afrag[3];
                #pragma unroll
                for (int nt = 0; nt < 4; ++nt) {
                    int yy = 2 * nt + coly + ki;
                    int xx = wn2 * 8 + colx + kj;
                    bfrag[nt] = *(const bf16x8*)&in_s[(yy * 18 + xx) * 32 + kg * 8];
                }
                #pragma unroll
                for (int mt = 0; mt < 3; ++mt)
                    afrag[mt] = *(const bf16x8*)
                        &w_s[cur * 6144 + t2 * 3072 + (om * 48 + mt * 16 + col) * 32 + kg * 8];
                #pragma unroll
                for (int mt = 0; mt < 3; ++mt)
                    #pragma unroll
                    for (int nt = 0; nt < 4; ++nt)
                        acc[mt][nt] = __builtin_amdgcn_mfma_f32_16x16x32_bf16(
                            afrag[mt], bfrag[nt], acc[mt][nt], 0, 0, 0);
            }
            __syncthreads();
        }
    }

    float stdv = stdp[0], biasv = biasp[0];
    float inv2s2 = 1.f / (2.f * stdv * stdv);
    #pragma unroll
    for (int nt = 0; nt < 4; ++nt) {
        int y = y0 + 2 * nt + coly;
        int x = x0 + wn2 * 8 + colx;
        int ly = 2 * nt + coly + 1, lx = wn2 * 8 + colx + 1;
        float pnv = 0.f;
        #pragma unroll
        for (int dy = -1; dy <= 1; ++dy)
            #pragma unroll
            for (int dx = -1; dx <= 1; ++dx)
                pnv += pnacc[(ly + dy) * 18 + (lx + dx)];
        #pragma unroll
        for (int mt = 0; mt < 3; ++mt) {
            int ob = o0 + om * 48 + mt * 16 + (kg << 2);
            #pragma unroll
            for (int r = 0; r < 4; ++r) {
                float d2 = fmaxf(pnv + wn[ob + r] - 2.f * acc[mt][nt][r], 0.f);
                float g = __expf(-d2 * inv2s2);
                g = (g >= biasv) ? g : 0.f;
                hout[((size_t)b * 384 + ob + r) * 1024 + y * 32 + x] = f2bf(g);
            }
        }
    }
}

// ---- fc chunk (ch in [0,768)) ----
__device__ __forceinline__ void dev_fc(int ch, int tid, unsigned char* smem,
    const unsigned short* __restrict__ h3bf, const float* __restrict__ fw,
    float* __restrict__ fcp, int* __restrict__ flags)
{
    unsigned short* h3s = (unsigned short*)smem;             // 8320
    unsigned short* fws = (unsigned short*)(smem + 16640);   // 8320
    float* red          = (float*)(smem + 33280);            // [4][16][16]
    int* s_nz           = (int*)(smem + 37376);              // 4
    __syncthreads();

    const size_t KI = 393216;
    int i0 = ch * 512;
    int lane = tid & 63, wv = tid >> 6;
    int col = lane & 15, kg = lane >> 4;

    unsigned int nzbits = 0;
    #pragma unroll
    for (int it = 0; it < 4; ++it) {
        int c = tid + it * 256;
        int b = c >> 6, off = (c & 63) * 8;
        bf16x8 v = *(const bf16x8*)&h3bf[(size_t)b * KI + i0 + off];
        union { bf16x8 s; unsigned int u[4]; } cv; cv.s = v;
        nzbits |= cv.u[0] | cv.u[1] | cv.u[2] | cv.u[3];
        *(bf16x8*)&h3s[b * 520 + off] = v;
    }
    bool any = __any(nzbits != 0);
    if (lane == 0) s_nz[wv] = any ? 1 : 0;
    __syncthreads();
    int anyall = s_nz[0] | s_nz[1] | s_nz[2] | s_nz[3];
    if (!anyall) {
        if (tid == 0) flags[ch] = 0;
        return;
    }
    if (tid == 0) flags[ch] = 1;

    float4 pre[8];
    #pragma unroll
    for (int it = 0; it < 8; ++it) {
        int c = tid + it * 256;
        int row = c >> 7, off4 = (c & 127) * 4;
        pre[it] = (row < 100) ? *(const float4*)&fw[(size_t)row * KI + i0 + off4]
                              : make_float4(0.f, 0.f, 0.f, 0.f);
    }

    for (int jt = 0; jt < 7; ++jt) {
        int j0 = jt * 16;
        #pragma unroll
        for (int it = 0; it < 8; ++it) {
            int c = tid + it * 256;
            int row = c >> 7, off4 = (c & 127) * 4;
            *(ushort4*)&fws[row * 520 + off4] =
                make_ushort4(f2bf(pre[it].x), f2bf(pre[it].y), f2bf(pre[it].z), f2bf(pre[it].w));
        }
        if (jt < 6) {
            #pragma unroll
            for (int it = 0; it < 8; ++it) {
                int c = tid + it * 256;
                int row = c >> 7, off4 = (c & 127) * 4;
                int j = j0 + 16 + row;
                pre[it] = (j < 100) ? *(const float4*)&fw[(size_t)j * KI + i0 + off4]
                                    : make_float4(0.f, 0.f, 0.f, 0.f);
            }
        }
        __syncthreads();
        f32x4 acc = (f32x4){0.f, 0.f, 0.f, 0.f};
        #pragma unroll
        for (int s = 0; s < 4; ++s) {
            int k = wv * 128 + s * 32 + kg * 8;
            bf16x8 af = *(const bf16x8*)&fws[col * 520 + k];
            bf16x8 bg = *(const bf16x8*)&h3s[col * 520 + k];
            acc = __builtin_amdgcn_mfma_f32_16x16x32_bf16(af, bg, acc, 0, 0, 0);
        }
        #pragma unroll
        for (int r = 0; r < 4; ++r) red[wv * 256 + (kg * 4 + r) * 16 + col] = acc[r];
        __syncthreads();
        int j = tid >> 4, bb = tid & 15;
        float s = red[0 * 256 + j * 16 + bb] + red[1 * 256 + j * 16 + bb] +
                  red[2 * 256 + j * 16 + bb] + red[3 * 256 + j * 16 + bb];
        fcp[((size_t)ch * 112 + j0 + j) * 16 + bb] = s;
    }
}

// ---- final (j in [0,100), lanes 0..63) ----
__device__ __forceinline__ void dev_final(int j, int lane,
    const float* __restrict__ fcp, const int* __restrict__ flags,
    const float* __restrict__ fb, float* __restrict__ outp)
{
    float acc[16];
    #pragma unroll
    for (int b = 0; b < 16; ++b) acc[b] = 0.f;
    for (int ch = lane; ch < 768; ch += 64) {
        if (flags[ch]) {
            const float* p = &fcp[((size_t)ch * 112 + j) * 16];
            #pragma unroll
            for (int b = 0; b < 16; ++b) acc[b] += p[b];
        }
    }
    #pragma unroll
    for (int off = 32; off >= 1; off >>= 1)
        #pragma unroll
        for (int b = 0; b < 16; ++b) acc[b] += __shfl_down(acc[b], off);
    if (lane == 0) {
        float bj = fb[j];
        #pragma unroll
        for (int b = 0; b < 16; ++b) outp[b * 100 + j] = bj + acc[b];
    }
}

// ================= mega (cooperative) kernel =================
__launch_bounds__(256, 2)
__global__ void mega(const float* x, const float* w1, const float* w2, const float* w3,
                     const float* std1, const float* bias1, const float* alpha1,
                     const float* std2, const float* bias2, const float* alpha2,
                     const float* std3, const float* bias3,
                     const float* fc_w, const float* fc_b, float* out,
                     float* sbuf, float* fcp, float* wn1, float* wn2, float* wn3,
                     int* flags,
                     unsigned short* h1bf, unsigned short* h2bf, unsigned short* h3bf,
                     unsigned short* xbf, unsigned short* w1r, unsigned short* w2r,
                     unsigned short* w3r, unsigned short* zerob)
{
    __shared__ __align__(16) unsigned char smem[65488];
    cg::grid_group grid = cg::this_grid();
    int bid = blockIdx.x;   // 0..511
    int tid = threadIdx.x;

    // phase 0: prep
    dev_prep(bid * 256 + tid, 512 * 256, x, w1, w2, w3, xbf, w1r, w2r, w3r, zerob);
    if (bid < 168) dev_wn(bid * 4 + (tid >> 6), tid & 63, w1, w2, w3, wn1, wn2, wn3);
    grid.sync();

    // phase 1: conv1 (1024 tiles, 2 per block)
    for (int t = bid; t < 1024; t += 512)
        dev_conv1(t, tid, smem, xbf, w1r, wn1, std1, bias1, alpha1, h1bf, sbuf);
    grid.sync();

    // phase 2: conv2 (512 tiles)
    dev_conv2(bid, tid, smem, h1bf, w2r, sbuf, wn2, std2, bias2, alpha2, zerob, h2bf);
    grid.sync();

    // phase 3: conv3 (512 tiles)
    dev_conv3(bid, tid, smem, h2bf, w3r, wn3, std3, bias3, zerob, h3bf);
    grid.sync();

    // phase 4: fc (768 chunks)
    for (int ch = bid; ch < 768; ch += 512)
        dev_fc(ch, tid, smem, h3bf, fc_w, fcp, flags);
    grid.sync();

    // phase 5: final (100 rows)
    if (bid < 100 && tid < 64)
        dev_final(bid, tid, fcp, flags, fc_b, out);
}

// ================= fallback standalone kernels =================
__launch_bounds__(256)
__global__ void k_prep(const float* x, const float* w1, const float* w2, const float* w3,
                       unsigned short* xbf, unsigned short* w1r, unsigned short* w2r,
                       unsigned short* w3r, unsigned short* zerob,
                       float* wn1, float* wn2, float* wn3) {
    dev_prep(blockIdx.x * 256 + threadIdx.x, 2048 * 256, x, w1, w2, w3,
             xbf, w1r, w2r, w3r, zerob);
    if (blockIdx.x < 168)
        dev_wn(blockIdx.x * 4 + (threadIdx.x >> 6), threadIdx.x & 63,
               w1, w2, w3, wn1, wn2, wn3);
}

__launch_bounds__(256, 2)
__global__ void k_conv1(const unsigned short* xbf, const unsigned short* w1r,
                        const float* wn, const float* stdp, const float* biasp,
                        const float* alphap, unsigned short* out, float* sqout) {
    __shared__ __align__(16) unsigned char smem[29696];
    dev_conv1(blockIdx.x, threadIdx.x, smem, xbf, w1r, wn, stdp, biasp, alphap, out, sqout);
}

__launch_bounds__(256, 2)
__global__ void k_conv2(const unsigned short* hin, const unsigned short* wt2,
                        const float* sq1, const float* wn, const float* stdp,
                        const float* biasp, const float* alphap,
                        const unsigned short* zerob, unsigned short* hout) {
    __shared__ __align__(16) unsigned char smem[65488];
    dev_conv2(blockIdx.x, threadIdx.x, smem, hin, wt2, sq1, wn, stdp, biasp, alphap,
              zerob, hout);
}

__launch_bounds__(256, 2)
__global__ void k_conv3(const unsigned short* hin, const unsigned short* wt3,
                        const float* wn, const float* stdp, const float* biasp,
                        const unsigned short* zerob, unsigned short* hout) {
    __shared__ __align__(16) unsigned char smem[36864];
    dev_conv3(blockIdx.x, threadIdx.x, smem, hin, wt3, wn, stdp, biasp, zerob, hout);
}

__launch_bounds__(256, 2)
__global__ void k_fc(const unsigned short* h3bf, const float* fw, float* fcp, int* flags) {
    __shared__ __align__(16) unsigned char smem[37392];
    dev_fc(blockIdx.x, threadIdx.x, smem, h3bf, fw, fcp, flags);
}

__global__ void k_final(const float* fcp, const int* flags, const float* fb, float* outp) {
    dev_final(blockIdx.x, threadIdx.x, fcp, flags, fb, outp);
}

// ================= launch =================
extern "C" void kernel_launch(void* const* d_in, const int* in_sizes, int n_in,
                              void* d_out, int out_size, void* d_ws, size_t ws_size,
                              hipStream_t stream) {
    const float* x      = (const float*)d_in[0];
    const float* w1     = (const float*)d_in[1];
    const float* std1   = (const float*)d_in[2];
    const float* bias1  = (const float*)d_in[3];
    const float* alpha1 = (const float*)d_in[4];
    const float* w2     = (const float*)d_in[5];
    const float* std2   = (const float*)d_in[6];
    const float* bias2  = (const float*)d_in[7];
    const float* alpha2 = (const float*)d_in[8];
    const float* w3     = (const float*)d_in[9];
    const float* std3   = (const float*)d_in[10];
    const float* bias3  = (const float*)d_in[11];
    const float* fc_w   = (const float*)d_in[12];
    const float* fc_b   = (const float*)d_in[13];
    float* out = (float*)d_out;
    float* ws  = (float*)d_ws;

    // float region
    float* sbuf  = ws;                  // 65536
    float* fcp   = sbuf + 65536;        // 1376256
    float* wn1   = fcp + 1376256;       // 96
    float* wn2   = wn1 + 96;            // 192
    float* wn3   = wn2 + 192;           // 384
    int*   flags = (int*)(wn3 + 384);   // 768
    float* rest  = wn3 + 384 + 768 + 32;
    // ushort region
    unsigned short* h1bf = (unsigned short*)rest;  // 6291456
    unsigned short* h2bf = h1bf + 6291456;         // 3145728
    unsigned short* h3bf = h2bf + 3145728;         // 6291456
    unsigned short* xbf  = h3bf + 6291456;         // 1048576
    unsigned short* w1r  = xbf + 1048576;          // 13056
    unsigned short* w2r  = w1r + 13056;            // 479232
    unsigned short* w3r  = w2r + 479232;           // 368640
    unsigned short* zerob = w3r + 368640;          // 64

    void* args[] = {
        (void*)&x, (void*)&w1, (void*)&w2, (void*)&w3,
        (void*)&std1, (void*)&bias1, (void*)&alpha1,
        (void*)&std2, (void*)&bias2, (void*)&alpha2,
        (void*)&std3, (void*)&bias3,
        (void*)&fc_w, (void*)&fc_b, (void*)&out,
        (void*)&sbuf, (void*)&fcp, (void*)&wn1, (void*)&wn2, (void*)&wn3,
        (void*)&flags,
        (void*)&h1bf, (void*)&h2bf, (void*)&h3bf,
        (void*)&xbf, (void*)&w1r, (void*)&w2r, (void*)&w3r, (void*)&zerob
    };
    hipError_t err = hipLaunchCooperativeKernel((const void*)mega, dim3(512), dim3(256),
                                                args, 0, stream);
    if (err != hipSuccess) {
        // fallback: separate-kernel chain (identical outputs)
        dim3 B(TPB);
        k_prep<<<dim3(2048), B, 0, stream>>>(x, w1, w2, w3, xbf, w1r, w2r, w3r, zerob,
                                             wn1, wn2, wn3);
        k_conv1<<<dim3(1024), B, 0, stream>>>(xbf, w1r, wn1, std1, bias1, alpha1,
                                              h1bf, sbuf);
        k_conv2<<<dim3(512), B, 0, stream>>>(h1bf, w2r, sbuf, wn2, std2, bias2, alpha2,
                                             zerob, h2bf);
        k_conv3<<<dim3(512), B, 0, stream>>>(h2bf, w3r, wn3, std3, bias3, zerob, h3bf);
        k_fc<<<dim3(768), B, 0, stream>>>(h3bf, fc_w, fcp, flags);
        k_final<<<dim3(100), dim3(64), 0, stream>>>(fcp, flags, fc_b, out);
    }
}

// Round 15
// 100.878 us; speedup vs baseline: 3.9080x; 3.9080x over previous
//
#include <hip/hip_runtime.h>

#define TPB 256

typedef short bf16x8 __attribute__((ext_vector_type(8)));
typedef float f32x4 __attribute__((ext_vector_type(4)));

__device__ inline unsigned short f2bf(float f) {
    unsigned int u = __float_as_uint(f);
    unsigned int r = (u + 0x7fffu + ((u >> 16) & 1u)) >> 16;
    return (unsigned short)r;
}
__device__ inline float bf2f(unsigned short h) {
    return __uint_as_float(((unsigned int)h) << 16);
}

// async global->LDS 16B copy (dest: linear wave-order, src: per-lane)
__device__ __forceinline__ void gl16(void* lds, const void* g) {
    __builtin_amdgcn_global_load_lds(
        (const __attribute__((address_space(1))) unsigned int*)g,
        (__attribute__((address_space(3))) unsigned int*)lds, 16, 0, 0);
}

// ---------- fused prep: xbf (+sq channel), all weight reorders, all weight norms ----------
__global__ void prep_all(const float* __restrict__ x,
                         const float* __restrict__ w1, const float* __restrict__ w2,
                         const float* __restrict__ w3,
                         unsigned short* __restrict__ xbf,
                         unsigned short* __restrict__ w1r, unsigned short* __restrict__ w2r,
                         unsigned short* __restrict__ w3r, unsigned short* __restrict__ zerob,
                         float* __restrict__ wn1, float* __restrict__ wn2,
                         float* __restrict__ wn3) {
    int bid = blockIdx.x;
    int tid = threadIdx.x;
    if (bid < 1024) {
        int idx = bid * TPB + tid;
        int b = idx >> 14, px = idx & 16383;
        const float* xb = x + (size_t)b * 3 * 16384 + px;
        float v0 = xb[0], v1 = xb[16384], v2 = xb[32768];
        ushort4 v;
        v.x = f2bf(v0); v.y = f2bf(v1); v.z = f2bf(v2);
        v.w = f2bf(v0 * v0 + v1 * v1 + v2 * v2);
        *(ushort4*)&xbf[(size_t)idx * 4] = v;
    } else if (bid < 4388) {
        int idx = (bid - 1024) * TPB + tid;
        if (idx < 13056) {
            int o = idx / 136, d = idx - o * 136;
            int tp = d >> 2, c = d & 3;
            float v = 0.f;
            if (tp < 30) {
                int ki = tp / 6, kj = tp - 6 * ki;
                if (kj < 5) v = (c < 3) ? w1[o * 75 + c * 25 + ki * 5 + kj] : -0.5f;
            }
            w1r[idx] = f2bf(v);
        } else if (idx < 492288) {
            int i = idx - 13056;
            int c = i & 31; int r = i >> 5;
            int o = r % 192; r /= 192;
            int tap = r % 26; int cg = r / 26;
            float v = 0.f;
            if (tap < 25) v = w2[((size_t)o * 96 + cg * 32 + c) * 25 + tap];
            w2r[i] = f2bf(v);
        } else if (idx < 860928) {
            int i = idx - 492288;
            int c = i & 31; int r = i >> 5;
            int o = r % 192; r /= 192;
            int tap = r % 10; int cg = r / 10;
            float v = 0.f;
            if (tap < 9) v = w3[((size_t)o * 192 + cg * 32 + c) * 9 + tap];
            w3r[i] = f2bf(v);
        } else if (idx < 860992) {
            zerob[idx - 860928] = 0;
        }
    } else {
        int o = (bid - 4388) * 4 + (tid >> 6);
        int lane = tid & 63;
        const float* row; float* dst; int D;
        if (o < 96)       { row = w1 + (size_t)o * 75;           D = 75;   dst = wn1 + o; }
        else if (o < 288) { int r = o - 96;  row = w2 + (size_t)r * 2400; D = 2400; dst = wn2 + r; }
        else              { int r = o - 288; row = w3 + (size_t)r * 1728; D = 1728; dst = wn3 + r; }
        float acc = 0.f;
        for (int i = lane; i < D; i += 64) { float v = row[i]; acc += v * v; }
        #pragma unroll
        for (int off = 32; off >= 1; off >>= 1) acc += __shfl_down(acc, off);
        if (lane == 0) *dst = acc;
    }
}

// ---------- conv1: MFMA bf16, K=128 (32 taps x 4c, c3 = -0.5*sq -> pn folded in) ----------
__launch_bounds__(256, 2)
__global__ void conv1_mfma(const unsigned short* __restrict__ xbf,
                           const unsigned short* __restrict__ w1r,
                           const float* __restrict__ wn,
                           const float* __restrict__ stdp, const float* __restrict__ biasp,
                           const float* __restrict__ alphap,
                           unsigned short* __restrict__ out,  // [16][64][64][96] bf16 CL
                           float* __restrict__ sqout)         // [16][64][64] fp32
{
    __shared__ unsigned short in_s[22 * 20 * 4];
    __shared__ unsigned short w_s[96 * 136];

    int bid = blockIdx.x;
    int tx = bid & 7; bid >>= 3;
    int ty = bid & 7; bid >>= 3;
    int b = bid;
    int x0 = tx * 16, y0 = ty * 16;
    int tid = threadIdx.x;
    int lane = tid & 63, wv = tid >> 6;
    int col = lane & 15, kg = lane >> 4;

    for (int idx = tid; idx < 21 * 20; idx += 256) {
        int py = idx / 20, px = idx - py * 20;
        int gy = y0 - 2 + py, gx = x0 - 2 + px;
        ushort4 v = make_ushort4(0, 0, 0, 0);
        if (gy >= 0 && gy < 128 && gx >= 0 && gx < 128)
            v = *(const ushort4*)&xbf[(((size_t)b * 128 + gy) * 128 + gx) * 4];
        *(ushort4*)&in_s[idx * 4] = v;
    }
    for (int idx = tid; idx < 1632; idx += 256)
        *(bf16x8*)&w_s[idx * 8] = *(const bf16x8*)&w1r[idx * 8];
    __syncthreads();

    f32x4 acc[6][4];
    #pragma unroll
    for (int mt = 0; mt < 6; ++mt)
        #pragma unroll
        for (int n = 0; n < 4; ++n) acc[mt][n] = (f32x4){0.f, 0.f, 0.f, 0.f};

    #pragma unroll
    for (int ks = 0; ks < 4; ++ks) {
        int tap0 = ks * 8 + kg * 2;
        int ki = tap0 / 6, kj = tap0 - 6 * ki;
        bf16x8 bfrag[4];
        #pragma unroll
        for (int n = 0; n < 4; ++n) {
            int row = wv * 4 + n + ki;
            int ix = col + kj;
            const unsigned short* p = &in_s[(row * 20 + ix) * 4];
            union { bf16x8 v; uint2 u[2]; } tmp;
            tmp.u[0] = *(const uint2*)p;
            tmp.u[1] = *(const uint2*)(p + 4);
            bfrag[n] = tmp.v;
        }
        bf16x8 afrag[6];
        #pragma unroll
        for (int mt = 0; mt < 6; ++mt)
            afrag[mt] = *(const bf16x8*)&w_s[(mt * 16 + col) * 136 + ks * 32 + kg * 8];
        #pragma unroll
        for (int mt = 0; mt < 6; ++mt)
            #pragma unroll
            for (int n = 0; n < 4; ++n)
                acc[mt][n] = __builtin_amdgcn_mfma_f32_16x16x32_bf16(
                    afrag[mt], bfrag[n], acc[mt][n], 0, 0, 0);
    }

    float stdv = stdp[0], biasv = biasp[0];
    float inv2s2 = 1.f / (2.f * stdv * stdv);
    float a00 = alphap[0], a01 = alphap[1], a10 = alphap[2], a11 = alphap[3];
    int dx = col & 1;
    float ax0 = dx ? a01 : a00;
    float ax1 = dx ? a11 : a10;

    float sqa[2] = {0.f, 0.f};
    #pragma unroll
    for (int mt = 0; mt < 6; ++mt) {
        #pragma unroll
        for (int p2 = 0; p2 < 2; ++p2) {
            unsigned short res[4];
            #pragma unroll
            for (int r = 0; r < 4; ++r) {
                int o = mt * 16 + kg * 4 + r;
                float wno = wn[o];
                float d20 = fmaxf(wno - 2.f * acc[mt][2 * p2][r], 0.f);
                float d21 = fmaxf(wno - 2.f * acc[mt][2 * p2 + 1][r], 0.f);
                float g0 = __expf(-d20 * inv2s2);
                float g1 = __expf(-d21 * inv2s2);
                g0 = (g0 >= biasv) ? g0 : 0.f;
                g1 = (g1 >= biasv) ? g1 : 0.f;
                float s = ax0 * g0 + ax1 * g1;
                s += __shfl_xor(s, 1);
                res[r] = f2bf(0.25f * s);
                float vv = bf2f(res[r]);
                sqa[p2] += vv * vv;
            }
            if (dx == 0) {
                int yo = ty * 8 + wv * 2 + p2, xo = tx * 8 + (col >> 1);
                *(ushort4*)&out[(((size_t)b * 64 + yo) * 64 + xo) * 96 + mt * 16 + kg * 4] =
                    make_ushort4(res[0], res[1], res[2], res[3]);
            }
        }
    }
    #pragma unroll
    for (int p2 = 0; p2 < 2; ++p2) {
        float s = sqa[p2];
        s += __shfl_xor(s, 16);
        s += __shfl_xor(s, 32);
        if (dx == 0 && kg == 0) {
            int yo = ty * 8 + wv * 2 + p2, xo = tx * 8 + (col >> 1);
            sqout[((size_t)b * 64 + yo) * 64 + xo] = s;
        }
    }
}

// ---------- conv2: 192o x 128px per block, 4 waves (2m x 2n), zero-skip before weights ----------
__launch_bounds__(256, 2)
__global__ void conv2_mfma(const unsigned short* __restrict__ hin,
                           const unsigned short* __restrict__ wt2,  // [3][26][192][32]
                           const float* __restrict__ sq1,           // [16][64][64] fp32
                           const float* __restrict__ wn,
                           const float* __restrict__ stdp, const float* __restrict__ biasp,
                           const float* __restrict__ alphap,
                           const unsigned short* __restrict__ zerob,
                           unsigned short* __restrict__ hout) // [16][32][32][192] CL bf16
{
    __shared__ unsigned short in_s[240 * 32];       // 15360 B
    __shared__ unsigned short w_s[2][2 * 192 * 32]; // 49152 B
    __shared__ float sq_s[240];
    __shared__ int s_nz[4];

    int bid = blockIdx.x;
    int xt = bid & 3; bid >>= 2;
    int yt = bid & 7; bid >>= 3;
    int b = bid;
    int x0 = xt * 16, y0 = yt * 8;
    int tid = threadIdx.x;
    int lane = tid & 63, wid = tid >> 6;
    int wave_m = wid >> 1, wave_n = wid & 1;
    int col = lane & 15, kg = lane >> 4;
    int coly = col >> 3, colx = col & 7;

    if (tid < 240) {
        int r = tid / 20, c = tid - r * 20;
        int gy = y0 - 2 + r, gx = x0 - 2 + c;
        float v = 0.f;
        if (gy >= 0 && gy < 64 && gx >= 0 && gx < 64)
            v = sq1[((size_t)b * 64 + gy) * 64 + gx];
        sq_s[tid] = v;
    }

    f32x4 acc[6][4];
    #pragma unroll
    for (int mt = 0; mt < 6; ++mt)
        #pragma unroll
        for (int nt = 0; nt < 4; ++nt) acc[mt][nt] = (f32x4){0.f, 0.f, 0.f, 0.f};

    for (int cg = 0; cg < 3; ++cg) {
        #pragma unroll
        for (int i = 0; i < 4; ++i) {
            int chunk = tid + i * 256;
            if (chunk < 960) {
                int px = chunk >> 2, c16 = chunk & 3;
                int iy = px / 20, ix = px - iy * 20;
                int gy = y0 - 2 + iy, gx = x0 - 2 + ix;
                const void* src = (gy >= 0 && gy < 64 && gx >= 0 && gx < 64)
                    ? (const void*)&hin[(((size_t)b * 64 + gy) * 64 + gx) * 96 + cg * 32 + c16 * 8]
                    : (const void*)zerob;
                gl16(&in_s[chunk * 8], src);
            }
        }
        __syncthreads();   // in_s ready

        unsigned int nzb = 0;
        #pragma unroll
        for (int i = 0; i < 4; ++i) {
            int chunk = tid + i * 256;
            if (chunk < 960) {
                uint4 v = *(const uint4*)&in_s[chunk * 8];
                nzb |= v.x | v.y | v.z | v.w;
            }
        }
        bool any = __any(nzb != 0);
        if (lane == 0) s_nz[wid] = any ? 1 : 0;
        __syncthreads();
        if (s_nz[0] | s_nz[1] | s_nz[2] | s_nz[3]) {
            #pragma unroll
            for (int i = 0; i < 6; ++i) {
                int chunk = tid + i * 256;
                int tp = chunk / 768, rem = chunk - tp * 768;
                gl16(&w_s[0][tp * 6144 + rem * 8],
                     &wt2[(((size_t)cg * 26 + tp) * 192) * 32 + rem * 8]);
            }
            __syncthreads();
            for (int pr = 0; pr < 13; ++pr) {
                int cur = pr & 1;
                if (pr < 12) {
                    #pragma unroll
                    for (int i = 0; i < 6; ++i) {
                        int chunk = tid + i * 256;
                        int tp = chunk / 768, rem = chunk - tp * 768;
                        gl16(&w_s[cur ^ 1][tp * 6144 + rem * 8],
                             &wt2[(((size_t)cg * 26 + (pr + 1) * 2 + tp) * 192) * 32 + rem * 8]);
                    }
                }
                #pragma unroll
                for (int t2 = 0; t2 < 2; ++t2) {
                    int tap = pr * 2 + t2;
                    int ki = tap / 5, kj = tap - 5 * ki;
                    if (tap >= 25) { ki = 0; kj = 0; }
                    bf16x8 bfrag[4], afrag[6];
                    #pragma unroll
                    for (int nt = 0; nt < 4; ++nt) {
                        int yy = 2 * nt + coly + ki;
                        int xx = wave_n * 8 + colx + kj;
                        bfrag[nt] = *(const bf16x8*)&in_s[(yy * 20 + xx) * 32 + kg * 8];
                    }
                    #pragma unroll
                    for (int mt = 0; mt < 6; ++mt)
                        afrag[mt] = *(const bf16x8*)
                            &w_s[cur][t2 * 6144 + (wave_m * 96 + mt * 16 + col) * 32 + kg * 8];
                    #pragma unroll
                    for (int mt = 0; mt < 6; ++mt)
                        #pragma unroll
                        for (int nt = 0; nt < 4; ++nt)
                            acc[mt][nt] = __builtin_amdgcn_mfma_f32_16x16x32_bf16(
                                afrag[mt], bfrag[nt], acc[mt][nt], 0, 0, 0);
                }
                __syncthreads();
            }
        }
    }

    float stdv = stdp[0], biasv = biasp[0];
    float inv2s2 = 1.f / (2.f * stdv * stdv);
    float a_own = alphap[coly * 2 + (col & 1)];
    #pragma unroll
    for (int nt = 0; nt < 4; ++nt) {
        int ly = 2 * nt + coly + 2;
        int lx = wave_n * 8 + colx + 2;
        float pnv = 0.f;
        #pragma unroll
        for (int dy = -2; dy <= 2; ++dy)
            #pragma unroll
            for (int dx2 = -2; dx2 <= 2; ++dx2)
                pnv += sq_s[(ly + dy) * 20 + (lx + dx2)];
        int x = x0 + wave_n * 8 + colx;
        int yo = (y0 >> 1) + nt;
        int xo = x >> 1;
        #pragma unroll
        for (int mt = 0; mt < 6; ++mt) {
            int ob = wave_m * 96 + mt * 16 + (kg << 2);
            unsigned short res[4];
            #pragma unroll
            for (int r = 0; r < 4; ++r) {
                float d2 = fmaxf(pnv + wn[ob + r] - 2.f * acc[mt][nt][r], 0.f);
                float g = __expf(-d2 * inv2s2);
                g = (g >= biasv) ? g : 0.f;
                g *= a_own;
                g += __shfl_xor(g, 1);
                g += __shfl_xor(g, 8);
                res[r] = f2bf(0.25f * g);
            }
            if (((col & 1) == 0) && ((col & 8) == 0)) {
                *(ushort4*)&hout[(((size_t)b * 32 + yo) * 32 + xo) * 192 + ob] =
                    make_ushort4(res[0], res[1], res[2], res[3]);
            }
        }
    }
}

// ---------- conv3: MFMA bf16, grid 512, 4 waves x (48o x 64px), 16x8 tile, inline pn3 ----------
__launch_bounds__(256, 2)
__global__ void conv3_mfma(const unsigned short* __restrict__ hin,  // [16][32][32][192] CL
                           const unsigned short* __restrict__ wt3,  // [6][10][192][32]
                           const float* __restrict__ wn,
                           const float* __restrict__ stdp, const float* __restrict__ biasp,
                           const unsigned short* __restrict__ zerob,
                           unsigned short* __restrict__ hout) // [16][384*1024] bf16 CF
{
    __shared__ unsigned short in_s[180 * 32];      // [10][18][32c] 11520 B
    __shared__ unsigned short w_s[2][2 * 96 * 32]; // 24576 B
    __shared__ float pnacc[180];

    int bid = blockIdx.x;
    int sp = bid & 7; bid >>= 3;
    int ot = bid & 3; int b = bid >> 2;
    int x0 = (sp & 1) * 16, y0 = (sp >> 1) * 8, o0 = ot * 96;
    int tid = threadIdx.x;
    int lane = tid & 63, wid = tid >> 6;
    int om = wid >> 1, wn2 = wid & 1;
    int col = lane & 15, kg = lane >> 4;
    int coly = col >> 3, colx = col & 7;

    if (tid < 180) pnacc[tid] = 0.f;

    f32x4 acc[3][4];
    #pragma unroll
    for (int mt = 0; mt < 3; ++mt)
        #pragma unroll
        for (int nt = 0; nt < 4; ++nt) acc[mt][nt] = (f32x4){0.f, 0.f, 0.f, 0.f};

    for (int cg = 0; cg < 6; ++cg) {
        #pragma unroll
        for (int i = 0; i < 3; ++i) {
            int chunk = tid + i * 256;
            if (chunk < 720) {
                int px = chunk >> 2, c16 = chunk & 3;
                int iy = px / 18, ix = px - iy * 18;
                int gy = y0 - 1 + iy, gx = x0 - 1 + ix;
                const void* src = (gy >= 0 && gy < 32 && gx >= 0 && gx < 32)
                    ? (const void*)&hin[(((size_t)b * 32 + gy) * 32 + gx) * 192 + cg * 32 + c16 * 8]
                    : (const void*)zerob;
                gl16(&in_s[chunk * 8], src);
            }
        }
        #pragma unroll
        for (int i = 0; i < 3; ++i) {
            int chunk = tid + i * 256;
            int tp = chunk / 384, rem = chunk - tp * 384;
            gl16(&w_s[0][tp * 3072 + rem * 8],
                 &wt3[(((size_t)cg * 10 + tp) * 192 + o0) * 32 + rem * 8]);
        }
        __syncthreads();

        if (tid < 180) {
            const unsigned short* p = &in_s[tid * 32];
            float a = 0.f;
            #pragma unroll
            for (int c = 0; c < 32; c += 8) {
                bf16x8 v = *(const bf16x8*)&p[c];
                #pragma unroll
                for (int j = 0; j < 8; ++j) { float f = bf2f((unsigned short)v[j]); a += f * f; }
            }
            pnacc[tid] += a;
        }

        for (int pr = 0; pr < 5; ++pr) {
            int cur = pr & 1;
            if (pr < 4) {
                #pragma unroll
                for (int i = 0; i < 3; ++i) {
                    int chunk = tid + i * 256;
                    int tp = chunk / 384, rem = chunk - tp * 384;
                    gl16(&w_s[cur ^ 1][tp * 3072 + rem * 8],
                         &wt3[(((size_t)cg * 10 + (pr + 1) * 2 + tp) * 192 + o0) * 32 + rem * 8]);
                }
            }
            #pragma unroll
            for (int t2 = 0; t2 < 2; ++t2) {
                int tap = pr * 2 + t2;
                int ki = tap / 3, kj = tap - 3 * ki;
                if (tap >= 9) { ki = 0; kj = 0; }
                bf16x8 bfrag[4], afrag[3];
                #pragma unroll
                for (int nt = 0; nt < 4; ++nt) {
                    int yy = 2 * nt + coly + ki;
                    int xx = wn2 * 8 + colx + kj;
                    bfrag[nt] = *(const bf16x8*)&in_s[(yy * 18 + xx) * 32 + kg * 8];
                }
                #pragma unroll
                for (int mt = 0; mt < 3; ++mt)
                    afrag[mt] = *(const bf16x8*)
                        &w_s[cur][(t2 * 96 + om * 48 + mt * 16 + col) * 32 + kg * 8];
                #pragma unroll
                for (int mt = 0; mt < 3; ++mt)
                    #pragma unroll
                    for (int nt = 0; nt < 4; ++nt)
                        acc[mt][nt] = __builtin_amdgcn_mfma_f32_16x16x32_bf16(
                            afrag[mt], bfrag[nt], acc[mt][nt], 0, 0, 0);
            }
            __syncthreads();
        }
    }

    float stdv = stdp[0], biasv = biasp[0];
    float inv2s2 = 1.f / (2.f * stdv * stdv);
    #pragma unroll
    for (int nt = 0; nt < 4; ++nt) {
        int y = y0 + 2 * nt + coly;
        int x = x0 + wn2 * 8 + colx;
        int ly = 2 * nt + coly + 1, lx = wn2 * 8 + colx + 1;
        float pnv = 0.f;
        #pragma unroll
        for (int dy = -1; dy <= 1; ++dy)
            #pragma unroll
            for (int dx = -1; dx <= 1; ++dx)
                pnv += pnacc[(ly + dy) * 18 + (lx + dx)];
        #pragma unroll
        for (int mt = 0; mt < 3; ++mt) {
            int ob = o0 + om * 48 + mt * 16 + (kg << 2);
            #pragma unroll
            for (int r = 0; r < 4; ++r) {
                float d2 = fmaxf(pnv + wn[ob + r] - 2.f * acc[mt][nt][r], 0.f);
                float g = __expf(-d2 * inv2s2);
                g = (g >= biasv) ? g : 0.f;
                hout[((size_t)b * 384 + ob + r) * 1024 + y * 32 + x] = f2bf(g);
            }
        }
    }
}

// ---------- FC: MFMA over K-chunks with exact zero-chunk skip ----------
__launch_bounds__(256, 4)
__global__ void fc_mfma(const unsigned short* __restrict__ h3bf,
                        const float* __restrict__ fw,
                        float* __restrict__ fcp,  // [768][112][16]
                        int* __restrict__ flags)  // [768]
{
    __shared__ unsigned short h3s[16 * 520];
    __shared__ unsigned short fws[16 * 520];
    __shared__ float red[4][16][16];
    __shared__ int s_nz[4];
    const size_t KI = 393216;
    int ch = blockIdx.x;
    int i0 = ch * 512;
    int tid = threadIdx.x;
    int lane = tid & 63, wv = tid >> 6;
    int col = lane & 15, kg = lane >> 4;

    unsigned int nzbits = 0;
    #pragma unroll
    for (int it = 0; it < 4; ++it) {
        int c = tid + it * 256;
        int b = c >> 6, off = (c & 63) * 8;
        bf16x8 v = *(const bf16x8*)&h3bf[(size_t)b * KI + i0 + off];
        union { bf16x8 s; unsigned int u[4]; } cv; cv.s = v;
        nzbits |= cv.u[0] | cv.u[1] | cv.u[2] | cv.u[3];
        *(bf16x8*)&h3s[b * 520 + off] = v;
    }
    bool any = __any(nzbits != 0);
    if (lane == 0) s_nz[wv] = any ? 1 : 0;
    __syncthreads();
    int anyall = s_nz[0] | s_nz[1] | s_nz[2] | s_nz[3];
    if (!anyall) {
        if (tid == 0) flags[ch] = 0;
        return;
    }
    if (tid == 0) flags[ch] = 1;

    float4 pre[8];
    #pragma unroll
    for (int it = 0; it < 8; ++it) {
        int c = tid + it * 256;
        int row = c >> 7, off4 = (c & 127) * 4;
        pre[it] = (row < 100) ? *(const float4*)&fw[(size_t)row * KI + i0 + off4]
                              : make_float4(0.f, 0.f, 0.f, 0.f);
    }

    for (int jt = 0; jt < 7; ++jt) {
        int j0 = jt * 16;
        #pragma unroll
        for (int it = 0; it < 8; ++it) {
            int c = tid + it * 256;
            int row = c >> 7, off4 = (c & 127) * 4;
            *(ushort4*)&fws[row * 520 + off4] =
                make_ushort4(f2bf(pre[it].x), f2bf(pre[it].y), f2bf(pre[it].z), f2bf(pre[it].w));
        }
        if (jt < 6) {
            #pragma unroll
            for (int it = 0; it < 8; ++it) {
                int c = tid + it * 256;
                int row = c >> 7, off4 = (c & 127) * 4;
                int j = j0 + 16 + row;
                pre[it] = (j < 100) ? *(const float4*)&fw[(size_t)j * KI + i0 + off4]
                                    : make_float4(0.f, 0.f, 0.f, 0.f);
            }
        }
        __syncthreads();
        f32x4 acc = (f32x4){0.f, 0.f, 0.f, 0.f};
        #pragma unroll
        for (int s = 0; s < 4; ++s) {
            int k = wv * 128 + s * 32 + kg * 8;
            bf16x8 af = *(const bf16x8*)&fws[col * 520 + k];
            bf16x8 bg = *(const bf16x8*)&h3s[col * 520 + k];
            acc = __builtin_amdgcn_mfma_f32_16x16x32_bf16(af, bg, acc, 0, 0, 0);
        }
        #pragma unroll
        for (int r = 0; r < 4; ++r) red[wv][kg * 4 + r][col] = acc[r];
        __syncthreads();
        int j = tid >> 4, bb = tid & 15;
        float s = red[0][j][bb] + red[1][j][bb] + red[2][j][bb] + red[3][j][bb];
        fcp[((size_t)ch * 112 + j0 + j) * 16 + bb] = s;
    }
}

__global__ void fc_final(const float* __restrict__ fcp, const int* __restrict__ flags,
                         const float* __restrict__ fb, float* __restrict__ outp) {
    int j = blockIdx.x;
    int lane = threadIdx.x;
    float acc[16];
    #pragma unroll
    for (int b = 0; b < 16; ++b) acc[b] = 0.f;
    for (int ch = lane; ch < 768; ch += 64) {
        if (flags[ch]) {
            const float* p = &fcp[((size_t)ch * 112 + j) * 16];
            #pragma unroll
            for (int b = 0; b < 16; ++b) acc[b] += p[b];
        }
    }
    #pragma unroll
    for (int off = 32; off >= 1; off >>= 1)
        #pragma unroll
        for (int b = 0; b < 16; ++b) acc[b] += __shfl_down(acc[b], off);
    if (lane == 0) {
        float bj = fb[j];
        #pragma unroll
        for (int b = 0; b < 16; ++b) outp[b * 100 + j] = bj + acc[b];
    }
}

// ---------- launch ----------
extern "C" void kernel_launch(void* const* d_in, const int* in_sizes, int n_in,
                              void* d_out, int out_size, void* d_ws, size_t ws_size,
                              hipStream_t stream) {
    const float* x      = (const float*)d_in[0];
    const float* w1     = (const float*)d_in[1];
    const float* std1   = (const float*)d_in[2];
    const float* bias1  = (const float*)d_in[3];
    const float* alpha1 = (const float*)d_in[4];
    const float* w2     = (const float*)d_in[5];
    const float* std2   = (const float*)d_in[6];
    const float* bias2  = (const float*)d_in[7];
    const float* alpha2 = (const float*)d_in[8];
    const float* w3     = (const float*)d_in[9];
    const float* std3   = (const float*)d_in[10];
    const float* bias3  = (const float*)d_in[11];
    const float* fc_w   = (const float*)d_in[12];
    const float* fc_b   = (const float*)d_in[13];
    float* out = (float*)d_out;
    float* ws  = (float*)d_ws;

    // float region
    float* sbuf  = ws;                  // 65536 (sq1 plane 16*64*64)
    float* fcp   = sbuf + 65536;        // 1376256
    float* wn1   = fcp + 1376256;       // 96
    float* wn2   = wn1 + 96;            // 192
    float* wn3   = wn2 + 192;           // 384
    int*   flags = (int*)(wn3 + 384);   // 768
    float* rest  = wn3 + 384 + 768 + 32;
    // ushort region
    unsigned short* h1bf = (unsigned short*)rest;  // 6291456
    unsigned short* h2bf = h1bf + 6291456;         // 3145728
    unsigned short* h3bf = h2bf + 3145728;         // 6291456
    unsigned short* xbf  = h3bf + 6291456;         // 1048576
    unsigned short* w1r  = xbf + 1048576;          // 13056
    unsigned short* w2r  = w1r + 13056;            // 479232
    unsigned short* w3r  = w2r + 479232;           // 368640
    unsigned short* zerob = w3r + 368640;          // 64

    dim3 B(TPB);

    prep_all<<<dim3(4556), B, 0, stream>>>(x, w1, w2, w3, xbf, w1r, w2r, w3r, zerob,
                                           wn1, wn2, wn3);

    conv1_mfma<<<dim3(1024), B, 0, stream>>>(xbf, w1r, wn1, std1, bias1, alpha1,
                                             h1bf, sbuf);

    conv2_mfma<<<dim3(512), B, 0, stream>>>(
        h1bf, w2r, sbuf, wn2, std2, bias2, alpha2, zerob, h2bf);

    conv3_mfma<<<dim3(512), B, 0, stream>>>(
        h2bf, w3r, wn3, std3, bias3, zerob, h3bf);

    fc_mfma<<<dim3(768), B, 0, stream>>>(h3bf, fc_w, fcp, flags);
    fc_final<<<dim3(100), dim3(64), 0, stream>>>(fcp, flags, fc_b, out);
}